// Round 2
// baseline (347.111 us; speedup 1.0000x reference)
//
#include <hip/hip_runtime.h>

#define LMAXV 8
#define NCOL 81                  // (LMAX+1)^2
#define ROWB 324                 // bytes per output row (81 * 4, float32)
#define BLOCKSZ 64               // ONE wave per block: LDS 20736 B -> 7 blocks/CU
                                 // (vs 128 threads / 41472 B -> 3 blocks/CU = 6 waves)
#define BCHUNK (BLOCKSZ * ROWB)  // 20736 bytes per block, 16B-aligned
#define NU4 (BCHUNK / 16)        // 1296 uint4 per block

typedef unsigned int u32x4 __attribute__((ext_vector_type(4)));

// ---------- compile-time associated-Legendre coefficient table ----------
struct LMCoef { float c[5]; int T; int par; };

constexpr double cfact(int n) { double r = 1.0; for (int i = 2; i <= n; ++i) r *= (double)i; return r; }
constexpr double ccomb(int n, int k) { return cfact(n) / (cfact(k) * cfact(n - k)); }
constexpr double csqrt_(double x) { double g = x > 1.0 ? x : 1.0; for (int i = 0; i < 200; ++i) g = 0.5 * (g + x / g); return g; }
constexpr double CPI_ = 3.14159265358979323846;

// P_{l,m}(z,y) = norm * y^m * d^{l+m}/dz^{l+m} (z^2-1)^l
// expressed as z^par * sum_j c[j] * (z^2)^j  (the y^m factor applied at runtime)
constexpr LMCoef make_lm(int l, int m) {
  LMCoef r{{0.f, 0.f, 0.f, 0.f, 0.f}, 0, 0};
  const int n = l + m;
  const double norm = csqrt_((double)(2 * l + 1) / (4.0 * CPI_) * cfact(l - m) / cfact(l + m))
                      / ((double)(1 << l) * cfact(l));
  r.par = (l - m) & 1;
  r.T = (l - m) / 2 + 1;
  for (int j = 0; j < r.T; ++j) {
    const int p = 2 * j + r.par + n;   // p = 2k: power of z inside (z^2-1)^l expansion
    const int k = p / 2;
    const double c = ccomb(l, k) * (((l - k) & 1) ? -1.0 : 1.0) * (cfact(p) / cfact(p - n));
    r.c[j] = (float)(norm * c);
  }
  return r;
}

constexpr LMCoef G_LM[45] = {
  make_lm(0,0),
  make_lm(1,0), make_lm(1,1),
  make_lm(2,0), make_lm(2,1), make_lm(2,2),
  make_lm(3,0), make_lm(3,1), make_lm(3,2), make_lm(3,3),
  make_lm(4,0), make_lm(4,1), make_lm(4,2), make_lm(4,3), make_lm(4,4),
  make_lm(5,0), make_lm(5,1), make_lm(5,2), make_lm(5,3), make_lm(5,4), make_lm(5,5),
  make_lm(6,0), make_lm(6,1), make_lm(6,2), make_lm(6,3), make_lm(6,4), make_lm(6,5), make_lm(6,6),
  make_lm(7,0), make_lm(7,1), make_lm(7,2), make_lm(7,3), make_lm(7,4), make_lm(7,5), make_lm(7,6), make_lm(7,7),
  make_lm(8,0), make_lm(8,1), make_lm(8,2), make_lm(8,3), make_lm(8,4), make_lm(8,5), make_lm(8,6), make_lm(8,7), make_lm(8,8)
};

// ------------------------------ kernel ------------------------------
__global__ __launch_bounds__(BLOCKSZ) void sh_ab_kernel(
    const float* __restrict__ alpha,
    const float* __restrict__ beta,
    float* __restrict__ out, int n)
{
  __shared__ u32x4 ldsbuf[NU4];
  float* lds = (float*)ldsbuf;

  const int tid = blockIdx.x * BLOCKSZ + threadIdx.x;

  float a = 0.f, b = 0.f;
  if (tid < n) {
    a = alpha[tid];               // float32 inputs
    b = beta[tid];
  }
  float sa, ca, sb, cbeta;
  __sincosf(a, &sa, &ca);
  __sincosf(b, &sb, &cbeta);
  const float z = cbeta, y = sb;
  const float z2 = z * z;

  // S[m] = sqrt2*sin(m*alpha), C[m] = sqrt2*cos(m*alpha)  (sqrt2 folded into seed)
  float S[LMAXV + 1], C[LMAXV + 1];
  S[1] = 1.41421356237309505f * sa;
  C[1] = 1.41421356237309505f * ca;
#pragma unroll
  for (int m = 2; m <= LMAXV; ++m) {
    C[m] = C[m - 1] * ca - S[m - 1] * sa;
    S[m] = S[m - 1] * ca + C[m - 1] * sa;
  }

  float YM[LMAXV + 1], ZYM[LMAXV + 1];
  YM[0] = 1.f;
#pragma unroll
  for (int m = 1; m <= LMAXV; ++m) YM[m] = YM[m - 1] * y;
#pragma unroll
  for (int m = 0; m <= LMAXV; ++m) ZYM[m] = z * YM[m];

  // per-thread row in LDS: stride 81 floats (odd stride -> conflict-free)
  float* myrow = lds + threadIdx.x * NCOL;

#pragma unroll
  for (int l = 0; l <= LMAXV; ++l) {
    float leg[LMAXV + 1];
#pragma unroll
    for (int mm = 0; mm <= l; ++mm) {
      const int idx = l * (l + 1) / 2 + mm;
      float v = 0.f;
#pragma unroll
      for (int j = 4; j >= 0; --j) {
        if (j < G_LM[idx].T) v = v * z2 + G_LM[idx].c[j];
      }
      leg[mm] = v * (G_LM[idx].par ? ZYM[mm] : YM[mm]);
    }
    const int colbase = l * l;
    // m = -l .. -1  -> sqrt2*sin(|m| a), descending |m|
#pragma unroll
    for (int j = 0; j < l; ++j) {
      myrow[colbase + j] = leg[l - j] * S[l - j];
    }
    // m = 0
    myrow[colbase + l] = leg[0];
    // m = 1 .. l -> sqrt2*cos(m a)
#pragma unroll
    for (int j = 1; j <= l; ++j) {
      myrow[colbase + l + j] = leg[j] * C[j];
    }
  }

  __syncthreads();   // single-wave block: effectively just a waitcnt

  // Block-cooperative coalesced copy-out: 20736 B = 1296 uint4 = 20.25/lane
  const u32x4* lsrc = (const u32x4*)lds;
  u32x4* gdst = (u32x4*)((char*)out + (size_t)blockIdx.x * BCHUNK);

  if (blockIdx.x != gridDim.x - 1) {
    // full block: no bounds checks (n % 64 == 0 for the bench shape anyway)
#pragma unroll
    for (int k = 0; k < 20; ++k) {
      const int o = threadIdx.x + (k << 6);
      gdst[o] = lsrc[o];
    }
    if (threadIdx.x < 16) {
      const int o = threadIdx.x + 1280;
      gdst[o] = lsrc[o];
    }
  } else {
    const long limitBytes = (long)n * ROWB - (long)blockIdx.x * BCHUNK;
    for (int o = threadIdx.x; o < NU4; o += BLOCKSZ) {
      if ((long)o * 16 < limitBytes) gdst[o] = lsrc[o];
    }
  }
}

// ------------------------------ launch ------------------------------
extern "C" void kernel_launch(void* const* d_in, const int* in_sizes, int n_in,
                              void* d_out, int out_size, void* d_ws, size_t ws_size,
                              hipStream_t stream) {
  const float* alpha = (const float*)d_in[0];
  const float* beta  = (const float*)d_in[1];
  float* out = (float*)d_out;
  const int n = in_sizes[0];
  const int grid = (n + BLOCKSZ - 1) / BLOCKSZ;
  hipLaunchKernelGGL(sh_ab_kernel, dim3(grid), dim3(BLOCKSZ), 0, stream,
                     alpha, beta, out, n);
}

// Round 3
// 343.894 us; speedup vs baseline: 1.0094x; 1.0094x over previous
//
#include <hip/hip_runtime.h>

#define LMAXV 8
#define NCOL 81                   // (LMAX+1)^2
#define ROWB 324                  // bytes per output row (81 * 4, float32)
#define BLOCKSZ 64                // one wave per block
#define TILES 4                   // 64-point tiles per block -> 256 pts/block
#define TILEB (BLOCKSZ * ROWB)    // 20736 bytes per tile
#define NU4T (TILEB / 16)         // 1296 uint4 per tile

typedef unsigned int u32x4 __attribute__((ext_vector_type(4)));

// ---------- compile-time associated-Legendre coefficient table ----------
struct LMCoef { float c[5]; int T; int par; };

constexpr double cfact(int n) { double r = 1.0; for (int i = 2; i <= n; ++i) r *= (double)i; return r; }
constexpr double ccomb(int n, int k) { return cfact(n) / (cfact(k) * cfact(n - k)); }
constexpr double csqrt_(double x) { double g = x > 1.0 ? x : 1.0; for (int i = 0; i < 200; ++i) g = 0.5 * (g + x / g); return g; }
constexpr double CPI_ = 3.14159265358979323846;

// P_{l,m}(z,y) = norm * y^m * d^{l+m}/dz^{l+m} (z^2-1)^l
// expressed as z^par * sum_j c[j] * (z^2)^j  (y^m factor applied at runtime)
constexpr LMCoef make_lm(int l, int m) {
  LMCoef r{{0.f, 0.f, 0.f, 0.f, 0.f}, 0, 0};
  const int n = l + m;
  const double norm = csqrt_((double)(2 * l + 1) / (4.0 * CPI_) * cfact(l - m) / cfact(l + m))
                      / ((double)(1 << l) * cfact(l));
  r.par = (l - m) & 1;
  r.T = (l - m) / 2 + 1;
  for (int j = 0; j < r.T; ++j) {
    const int p = 2 * j + r.par + n;
    const int k = p / 2;
    const double c = ccomb(l, k) * (((l - k) & 1) ? -1.0 : 1.0) * (cfact(p) / cfact(p - n));
    r.c[j] = (float)(norm * c);
  }
  return r;
}

constexpr LMCoef G_LM[45] = {
  make_lm(0,0),
  make_lm(1,0), make_lm(1,1),
  make_lm(2,0), make_lm(2,1), make_lm(2,2),
  make_lm(3,0), make_lm(3,1), make_lm(3,2), make_lm(3,3),
  make_lm(4,0), make_lm(4,1), make_lm(4,2), make_lm(4,3), make_lm(4,4),
  make_lm(5,0), make_lm(5,1), make_lm(5,2), make_lm(5,3), make_lm(5,4), make_lm(5,5),
  make_lm(6,0), make_lm(6,1), make_lm(6,2), make_lm(6,3), make_lm(6,4), make_lm(6,5), make_lm(6,6),
  make_lm(7,0), make_lm(7,1), make_lm(7,2), make_lm(7,3), make_lm(7,4), make_lm(7,5), make_lm(7,6), make_lm(7,7),
  make_lm(8,0), make_lm(8,1), make_lm(8,2), make_lm(8,3), make_lm(8,4), make_lm(8,5), make_lm(8,6), make_lm(8,7), make_lm(8,8)
};

// ---------------- per-tile compute: 64 rows into an LDS buffer ----------------
__device__ __forceinline__ void compute_tile(float* __restrict__ buf, int lane,
                                             float a, float b) {
  float sa, ca, sb, cbeta;
  __sincosf(a, &sa, &ca);
  __sincosf(b, &sb, &cbeta);
  const float z = cbeta, y = sb;
  const float z2 = z * z;

  // S[m] = sqrt2*sin(m*alpha), C[m] = sqrt2*cos(m*alpha)
  float S[LMAXV + 1], C[LMAXV + 1];
  S[1] = 1.41421356237309505f * sa;
  C[1] = 1.41421356237309505f * ca;
#pragma unroll
  for (int m = 2; m <= LMAXV; ++m) {
    C[m] = C[m - 1] * ca - S[m - 1] * sa;
    S[m] = S[m - 1] * ca + C[m - 1] * sa;
  }

  float YM[LMAXV + 1], ZYM[LMAXV + 1];
  YM[0] = 1.f;
#pragma unroll
  for (int m = 1; m <= LMAXV; ++m) YM[m] = YM[m - 1] * y;
#pragma unroll
  for (int m = 0; m <= LMAXV; ++m) ZYM[m] = z * YM[m];

  // per-thread row: stride 81 floats (odd stride -> conflict-free banks)
  float* myrow = buf + lane * NCOL;

#pragma unroll
  for (int l = 0; l <= LMAXV; ++l) {
    float leg[LMAXV + 1];
#pragma unroll
    for (int mm = 0; mm <= l; ++mm) {
      const int idx = l * (l + 1) / 2 + mm;
      float v = 0.f;
#pragma unroll
      for (int j = 4; j >= 0; --j) {
        if (j < G_LM[idx].T) v = v * z2 + G_LM[idx].c[j];
      }
      leg[mm] = v * (G_LM[idx].par ? ZYM[mm] : YM[mm]);
    }
    const int colbase = l * l;
#pragma unroll
    for (int j = 0; j < l; ++j) myrow[colbase + j] = leg[l - j] * S[l - j];
    myrow[colbase + l] = leg[0];
#pragma unroll
    for (int j = 1; j <= l; ++j) myrow[colbase + l + j] = leg[j] * C[j];
  }
}

// ------------------------------ kernel ------------------------------
__global__ __launch_bounds__(BLOCKSZ) void sh_ab_kernel(
    const float* __restrict__ alpha,
    const float* __restrict__ beta,
    float* __restrict__ out, int n)
{
  // double-buffered staging: 2 x 20736 B = 41472 B -> 3 blocks/CU (LDS-bound)
  __shared__ u32x4 bufA[NU4T];
  __shared__ u32x4 bufB[NU4T];

  const int lane = threadIdx.x;
  const long p0 = (long)blockIdx.x * (BLOCKSZ * TILES);

  // prefetch tile 0 inputs
  float a = 0.f, b = 0.f;
  {
    const long i = p0 + lane;
    if (i < n) { a = alpha[i]; b = beta[i]; }
  }

#pragma unroll
  for (int t = 0; t < TILES; ++t) {
    float* buf = (t & 1) ? (float*)bufB : (float*)bufA;
    const float at = a, bt = b;

    // prefetch next tile's inputs (loads fly under this tile's compute+copy)
    if (t + 1 < TILES) {
      const long i = p0 + (long)(t + 1) * BLOCKSZ + lane;
      a = 0.f; b = 0.f;
      if (i < n) { a = alpha[i]; b = beta[i]; }
    }

    compute_tile(buf, lane, at, bt);

    // single-wave block: LDS is in-order per wave; this wait delivers the
    // cross-lane ds_write data without draining vmcnt (stores stay in flight,
    // unlike __syncthreads which emits s_waitcnt vmcnt(0) lgkmcnt(0)).
    asm volatile("s_waitcnt lgkmcnt(0)" ::: "memory");

    // coalesced copy-out of this tile (nontemporal streaming stores)
    const long tbyte = (p0 + (long)t * BLOCKSZ) * ROWB;
    const long rem = (long)n * ROWB - tbyte;
    if (rem <= 0) break;
    const u32x4* ls = (const u32x4*)buf;
    u32x4* gd = (u32x4*)((char*)out + tbyte);

    if (rem >= TILEB) {
#pragma unroll
      for (int g = 0; g < 5; ++g) {
        u32x4 v0 = ls[lane + (g * 4 + 0) * 64];
        u32x4 v1 = ls[lane + (g * 4 + 1) * 64];
        u32x4 v2 = ls[lane + (g * 4 + 2) * 64];
        u32x4 v3 = ls[lane + (g * 4 + 3) * 64];
        __builtin_nontemporal_store(v0, &gd[lane + (g * 4 + 0) * 64]);
        __builtin_nontemporal_store(v1, &gd[lane + (g * 4 + 1) * 64]);
        __builtin_nontemporal_store(v2, &gd[lane + (g * 4 + 2) * 64]);
        __builtin_nontemporal_store(v3, &gd[lane + (g * 4 + 3) * 64]);
      }
      if (lane < 16) {
        u32x4 v = ls[1280 + lane];
        __builtin_nontemporal_store(v, &gd[1280 + lane]);
      }
    } else {
      for (int o = lane; o < NU4T; o += BLOCKSZ) {
        if ((long)o * 16 < rem) gd[o] = ls[o];
      }
    }
  }
}

// ------------------------------ launch ------------------------------
extern "C" void kernel_launch(void* const* d_in, const int* in_sizes, int n_in,
                              void* d_out, int out_size, void* d_ws, size_t ws_size,
                              hipStream_t stream) {
  const float* alpha = (const float*)d_in[0];
  const float* beta  = (const float*)d_in[1];
  float* out = (float*)d_out;
  const int n = in_sizes[0];
  const int ptsPerBlock = BLOCKSZ * TILES;
  const int grid = (n + ptsPerBlock - 1) / ptsPerBlock;
  hipLaunchKernelGGL(sh_ab_kernel, dim3(grid), dim3(BLOCKSZ), 0, stream,
                     alpha, beta, out, n);
}